// Round 1
// baseline (5369.877 us; speedup 1.0000x reference)
//
#include <hip/hip_runtime.h>
#include <hip/hip_bf16.h>
#include <cmath>

#define N_NODES 50000
#define IN_F 64
#define L 128
#define STEPS 3
#define T_TYPES 4
#define E_EDGES 800000

// ---------------- generic tiled matmul: C = act(A @ W^T + bias) ----------------
// A [N,K] row-major, W [OUT,K] row-major, C [N,OUT]. K multiple of 16, OUT multiple of 64.
#define BN 64
#define BO 64
#define BK 16

__global__ __launch_bounds__(256) void matmul_nt(
    const float* __restrict__ A, const float* __restrict__ W,
    const float* __restrict__ bias, float* __restrict__ C,
    int N, int K, int OUT, int relu_flag)
{
  __shared__ float As[BN][BK + 1];
  __shared__ float Ws[BO][BK + 1];
  const int tid = threadIdx.x;
  const int n_base = blockIdx.x * BN;
  const int o_base = blockIdx.y * BO;
  const int tx = tid & 15;       // out group
  const int ty = tid >> 4;       // node group
  const int n0 = ty * 4, o0 = tx * 4;
  const int lr = tid >> 2;       // load row 0..63
  const int lc = (tid & 3) * 4;  // load col {0,4,8,12}
  float acc[4][4] = {{0.f, 0.f, 0.f, 0.f}};
  for (int kc = 0; kc < K; kc += BK) {
    int gn = n_base + lr;
    float4 av = make_float4(0.f, 0.f, 0.f, 0.f);
    if (gn < N) av = *(const float4*)(A + (size_t)gn * K + kc + lc);
    As[lr][lc + 0] = av.x; As[lr][lc + 1] = av.y;
    As[lr][lc + 2] = av.z; As[lr][lc + 3] = av.w;
    float4 wv = *(const float4*)(W + (size_t)(o_base + lr) * K + kc + lc);
    Ws[lr][lc + 0] = wv.x; Ws[lr][lc + 1] = wv.y;
    Ws[lr][lc + 2] = wv.z; Ws[lr][lc + 3] = wv.w;
    __syncthreads();
#pragma unroll
    for (int kk = 0; kk < BK; ++kk) {
      float a[4], w[4];
#pragma unroll
      for (int i = 0; i < 4; ++i) a[i] = As[n0 + i][kk];
#pragma unroll
      for (int j = 0; j < 4; ++j) w[j] = Ws[o0 + j][kk];
#pragma unroll
      for (int i = 0; i < 4; ++i)
#pragma unroll
        for (int j = 0; j < 4; ++j) acc[i][j] += a[i] * w[j];
    }
    __syncthreads();
  }
#pragma unroll
  for (int i = 0; i < 4; ++i) {
    int gn = n_base + n0 + i;
    if (gn >= N) continue;
    int o = o_base + o0;
    float b0 = bias ? bias[o + 0] : 0.f;
    float b1 = bias ? bias[o + 1] : 0.f;
    float b2 = bias ? bias[o + 2] : 0.f;
    float b3 = bias ? bias[o + 3] : 0.f;
    float4 v;
    v.x = acc[i][0] + b0; v.y = acc[i][1] + b1;
    v.z = acc[i][2] + b2; v.w = acc[i][3] + b3;
    if (relu_flag) {
      v.x = fmaxf(v.x, 0.f); v.y = fmaxf(v.y, 0.f);
      v.z = fmaxf(v.z, 0.f); v.w = fmaxf(v.w, 0.f);
    }
    *(float4*)(C + (size_t)gn * OUT + o) = v;
  }
}

// ---------------- bond type = argmax over 4 edge_attr ----------------
__global__ __launch_bounds__(256) void bond_argmax(
    const float* __restrict__ ea, int* __restrict__ bond)
{
  int e = blockIdx.x * 256 + threadIdx.x;
  if (e >= E_EDGES) return;
  const float* a = ea + (size_t)e * T_TYPES;
  float bv = a[0]; int bi = 0;
#pragma unroll
  for (int t = 1; t < T_TYPES; ++t) {
    float v = a[t];
    if (v > bv) { bv = v; bi = t; }  // strict > keeps first max (jnp.argmax)
  }
  bond[e] = bi;
}

// ---------------- scatter: agg[dst] += 2*Ht[src] for edges of type t ----------------
__global__ __launch_bounds__(256) void scatter_add_type(
    const float* __restrict__ Ht, const int* __restrict__ ei,
    const int* __restrict__ bond, float* __restrict__ agg, int t)
{
  long long gid = (long long)blockIdx.x * 256 + threadIdx.x;
  int e = (int)(gid >> 5);
  if (e >= E_EDGES) return;
  if (bond[e] != t) return;
  int c = ((int)gid & 31) * 4;
  int s = ei[e];
  int d = ei[E_EDGES + e];
  float4 h = *(const float4*)(Ht + (size_t)s * L + c);
  float* ap = agg + (size_t)d * L + c;
  atomicAdd(ap + 0, 2.f * h.x);
  atomicAdd(ap + 1, 2.f * h.y);
  atomicAdd(ap + 2, 2.f * h.z);
  atomicAdd(ap + 3, 2.f * h.w);
}

// ---------------- fused GRU: gi matvec + gates + relu ----------------
// 16 nodes per block, 128 threads; thread j owns output dim j of all 3 gates.
__global__ __launch_bounds__(128) void gru_relu(
    const float* __restrict__ agg, const float* __restrict__ gh,
    const float* __restrict__ x0, const float* __restrict__ w_ih,
    const float* __restrict__ b_ih, float* __restrict__ m, int N)
{
  __shared__ float aggs[16][L];
  const int j = threadIdx.x;
  const int nb = blockIdx.x * 16;
#pragma unroll
  for (int r = 0; r < 16; ++r) {
    int gn = nb + r;
    aggs[r][j] = (gn < N) ? agg[(size_t)gn * L + j] : 0.f;
  }
  __syncthreads();
  float ar[16], az[16], an[16];
  const float br = b_ih[j], bz = b_ih[L + j], bn = b_ih[2 * L + j];
#pragma unroll
  for (int n = 0; n < 16; ++n) { ar[n] = br; az[n] = bz; an[n] = bn; }
  const float* wr = w_ih + (size_t)j * L;
  const float* wz = w_ih + (size_t)(L + j) * L;
  const float* wn = w_ih + (size_t)(2 * L + j) * L;
  for (int k = 0; k < L; k += 4) {
    float4 vr = *(const float4*)(wr + k);
    float4 vz = *(const float4*)(wz + k);
    float4 vn = *(const float4*)(wn + k);
#pragma unroll
    for (int n = 0; n < 16; ++n) {
      float4 a = *(const float4*)(&aggs[n][k]);  // broadcast across lanes
      ar[n] += vr.x * a.x + vr.y * a.y + vr.z * a.z + vr.w * a.w;
      az[n] += vz.x * a.x + vz.y * a.y + vz.z * a.z + vz.w * a.w;
      an[n] += vn.x * a.x + vn.y * a.y + vn.z * a.z + vn.w * a.w;
    }
  }
#pragma unroll
  for (int n = 0; n < 16; ++n) {
    int gn = nb + n;
    if (gn >= N) continue;
    float ghr = gh[(size_t)gn * 384 + j];
    float ghz = gh[(size_t)gn * 384 + L + j];
    float ghn = gh[(size_t)gn * 384 + 2 * L + j];
    float r = 1.f / (1.f + __expf(-(ar[n] + ghr)));
    float z = 1.f / (1.f + __expf(-(az[n] + ghz)));
    float t = tanhf(an[n] + r * ghn);
    float h = (1.f - z) * t + z * x0[(size_t)gn * L + j];
    m[(size_t)gn * L + j] = fmaxf(h, 0.f);
  }
}

extern "C" void kernel_launch(void* const* d_in, const int* in_sizes, int n_in,
                              void* d_out, int out_size, void* d_ws, size_t ws_size,
                              hipStream_t stream) {
  const float* x     = (const float*)d_in[0];
  const int*   ei    = (const int*)d_in[1];   // [2,E]: first E src, next E dst
  const float* eattr = (const float*)d_in[2];
  const float* lin_w = (const float*)d_in[3];
  const float* lin_b = (const float*)d_in[4];
  const float* gnn_w = (const float*)d_in[5];
  const float* w_ih  = (const float*)d_in[6];
  const float* w_hh  = (const float*)d_in[7];
  const float* b_ih  = (const float*)d_in[8];
  const float* b_hh  = (const float*)d_in[9];
  const float* mu_w  = (const float*)d_in[10];
  const float* mu_b  = (const float*)d_in[11];
  const float* lv_w  = (const float*)d_in[12];
  const float* lv_b  = (const float*)d_in[13];

  char* ws = (char*)d_ws;
  const size_t szNL = (size_t)N_NODES * L * sizeof(float);       // 25.6 MB
  const size_t szGH = (size_t)N_NODES * 3 * L * sizeof(float);   // 76.8 MB
  float* x0  = (float*)(ws);
  float* m   = (float*)(ws + szNL);
  float* agg = (float*)(ws + 2 * szNL);
  float* gh  = (float*)(ws + 3 * szNL);
  float* Ht  = (float*)(ws + 3 * szNL + szGH);
  int*   bond = (int*)(ws + 4 * szNL + szGH);

  dim3 blk(256);
  bond_argmax<<<(E_EDGES + 255) / 256, blk, 0, stream>>>(eattr, bond);

  dim3 g_x0((N_NODES + BN - 1) / BN, L / BO);
  matmul_nt<<<g_x0, blk, 0, stream>>>(x, lin_w, lin_b, x0, N_NODES, IN_F, L, 1);

  dim3 g_gh((N_NODES + BN - 1) / BN, (3 * L) / BO);
  matmul_nt<<<g_gh, blk, 0, stream>>>(x0, w_hh, b_hh, gh, N_NODES, L, 3 * L, 0);

  const float* mcur = x0;
  dim3 g_h((N_NODES + BN - 1) / BN, L / BO);
  for (int s = 0; s < STEPS; ++s) {
    hipMemsetAsync(agg, 0, szNL, stream);
    for (int t = 0; t < T_TYPES; ++t) {
      const float* Wt = gnn_w + ((size_t)s * T_TYPES + t) * L * L;
      matmul_nt<<<g_h, blk, 0, stream>>>(mcur, Wt, nullptr, Ht, N_NODES, L, L, 0);
      scatter_add_type<<<(E_EDGES * 32) / 256, blk, 0, stream>>>(Ht, ei, bond, agg, t);
    }
    gru_relu<<<N_NODES / 16, dim3(128), 0, stream>>>(agg, gh, x0, w_ih, b_ih, m, N_NODES);
    mcur = m;
  }

  float* mu = (float*)d_out;
  float* lv = (float*)d_out + (size_t)N_NODES * L;
  matmul_nt<<<g_h, blk, 0, stream>>>(mcur, mu_w, mu_b, mu, N_NODES, L, L, 0);
  matmul_nt<<<g_h, blk, 0, stream>>>(mcur, lv_w, lv_b, lv, N_NODES, L, L, 0);
}

// Round 2
// 1527.443 us; speedup vs baseline: 3.5156x; 3.5156x over previous
//
#include <hip/hip_runtime.h>
#include <hip/hip_bf16.h>
#include <cmath>

#define N_NODES 50000
#define IN_F 64
#define L 128
#define STEPS 3
#define T_TYPES 4
#define E_EDGES 800000

// ---------------- generic tiled matmul: C = act(A @ W^T + bias) ----------------
// A [N,K] row-major, W [OUT,K] row-major, C [N,OUT]. K multiple of 16, OUT multiple of 64.
// blockIdx.z selects W += z*w_zstride, C += z*c_zstride (for batched per-type H).
#define BN 64
#define BO 64
#define BK 16

__global__ __launch_bounds__(256) void matmul_nt(
    const float* __restrict__ A, const float* __restrict__ W,
    const float* __restrict__ bias, float* __restrict__ C,
    int N, int K, int OUT, int relu_flag,
    size_t w_zstride, size_t c_zstride)
{
  W += blockIdx.z * w_zstride;
  C += blockIdx.z * c_zstride;
  __shared__ float As[BN][BK + 1];
  __shared__ float Ws[BO][BK + 1];
  const int tid = threadIdx.x;
  const int n_base = blockIdx.x * BN;
  const int o_base = blockIdx.y * BO;
  const int tx = tid & 15;       // out group
  const int ty = tid >> 4;       // node group
  const int n0 = ty * 4, o0 = tx * 4;
  const int lr = tid >> 2;       // load row 0..63
  const int lc = (tid & 3) * 4;  // load col {0,4,8,12}
  float acc[4][4] = {{0.f, 0.f, 0.f, 0.f}};
  for (int kc = 0; kc < K; kc += BK) {
    int gn = n_base + lr;
    float4 av = make_float4(0.f, 0.f, 0.f, 0.f);
    if (gn < N) av = *(const float4*)(A + (size_t)gn * K + kc + lc);
    As[lr][lc + 0] = av.x; As[lr][lc + 1] = av.y;
    As[lr][lc + 2] = av.z; As[lr][lc + 3] = av.w;
    float4 wv = *(const float4*)(W + (size_t)(o_base + lr) * K + kc + lc);
    Ws[lr][lc + 0] = wv.x; Ws[lr][lc + 1] = wv.y;
    Ws[lr][lc + 2] = wv.z; Ws[lr][lc + 3] = wv.w;
    __syncthreads();
#pragma unroll
    for (int kk = 0; kk < BK; ++kk) {
      float a[4], w[4];
#pragma unroll
      for (int i = 0; i < 4; ++i) a[i] = As[n0 + i][kk];
#pragma unroll
      for (int j = 0; j < 4; ++j) w[j] = Ws[o0 + j][kk];
#pragma unroll
      for (int i = 0; i < 4; ++i)
#pragma unroll
        for (int j = 0; j < 4; ++j) acc[i][j] += a[i] * w[j];
    }
    __syncthreads();
  }
#pragma unroll
  for (int i = 0; i < 4; ++i) {
    int gn = n_base + n0 + i;
    if (gn >= N) continue;
    int o = o_base + o0;
    float b0 = bias ? bias[o + 0] : 0.f;
    float b1 = bias ? bias[o + 1] : 0.f;
    float b2 = bias ? bias[o + 2] : 0.f;
    float b3 = bias ? bias[o + 3] : 0.f;
    float4 v;
    v.x = acc[i][0] + b0; v.y = acc[i][1] + b1;
    v.z = acc[i][2] + b2; v.w = acc[i][3] + b3;
    if (relu_flag) {
      v.x = fmaxf(v.x, 0.f); v.y = fmaxf(v.y, 0.f);
      v.z = fmaxf(v.z, 0.f); v.w = fmaxf(v.w, 0.f);
    }
    *(float4*)(C + (size_t)gn * OUT + o) = v;
  }
}

// ---------------- CSR build ----------------
__global__ __launch_bounds__(256) void hist_dst(
    const int* __restrict__ ei, int* __restrict__ counts)
{
  int e = blockIdx.x * 256 + threadIdx.x;
  if (e >= E_EDGES) return;
  atomicAdd(&counts[ei[E_EDGES + e]], 1);
}

// single-block exclusive scan over n counts -> offsets
__global__ __launch_bounds__(1024) void scan_counts(
    const int* __restrict__ counts, int* __restrict__ offsets, int n)
{
  __shared__ int ls[1024];
  __shared__ int carry_s;
  const int tid = threadIdx.x;
  if (tid == 0) carry_s = 0;
  __syncthreads();
  for (int start = 0; start < n; start += 1024) {
    int i = start + tid;
    int v = (i < n) ? counts[i] : 0;
    ls[tid] = v;
    __syncthreads();
    for (int off = 1; off < 1024; off <<= 1) {
      int t = (tid >= off) ? ls[tid - off] : 0;
      __syncthreads();
      ls[tid] += t;
      __syncthreads();
    }
    int c = carry_s;
    if (i < n) offsets[i] = c + ls[tid] - v;  // exclusive
    __syncthreads();
    if (tid == 0) carry_s = c + ls[1023];
    __syncthreads();
  }
}

// fill sorted edge list: epacked[pos] = (bond<<20)|src, pos from cursor[dst]++
__global__ __launch_bounds__(256) void fill_csr(
    const int* __restrict__ ei, const float* __restrict__ ea,
    int* __restrict__ cursor, int* __restrict__ epacked)
{
  int e = blockIdx.x * 256 + threadIdx.x;
  if (e >= E_EDGES) return;
  const float* a = ea + (size_t)e * T_TYPES;
  float bv = a[0]; int bi = 0;
#pragma unroll
  for (int t = 1; t < T_TYPES; ++t) {
    float v = a[t];
    if (v > bv) { bv = v; bi = t; }  // strict > == jnp.argmax first-max
  }
  int d = ei[E_EDGES + e];
  int pos = atomicAdd(&cursor[d], 1);
  epacked[pos] = (bi << 20) | ei[e];
}

// ---------------- gather-reduce: agg[d] = 2 * sum_e H[bond_e][src_e] ----------------
// one wave (64 lanes) per node, lane owns 2 channels (float2)
__global__ __launch_bounds__(256) void gather_agg(
    const float* __restrict__ H, const int* __restrict__ offsets,
    const int* __restrict__ epacked, float* __restrict__ agg, int nNodes)
{
  const int wave = threadIdx.x >> 6;
  const int lane = threadIdx.x & 63;
  const int node = blockIdx.x * 4 + wave;
  if (node >= nNodes) return;
  const int beg = offsets[node];
  const int end = (node + 1 < nNodes) ? offsets[node + 1] : E_EDGES;
  float2 acc = make_float2(0.f, 0.f);
  for (int j = beg; j < end; ++j) {
    int p = epacked[j];
    int src = p & 0xFFFFF;
    int t = p >> 20;
    float2 h = *(const float2*)(H + ((size_t)t * N_NODES + src) * L + lane * 2);
    acc.x += h.x;
    acc.y += h.y;
  }
  float2* o = (float2*)(agg + (size_t)node * L + lane * 2);
  *o = make_float2(2.f * acc.x, 2.f * acc.y);
}

// ---------------- fused GRU: gi matvec + gates + relu ----------------
__global__ __launch_bounds__(128) void gru_relu(
    const float* __restrict__ agg, const float* __restrict__ gh,
    const float* __restrict__ x0, const float* __restrict__ w_ih,
    const float* __restrict__ b_ih, float* __restrict__ m, int N)
{
  __shared__ float aggs[16][L];
  const int j = threadIdx.x;
  const int nb = blockIdx.x * 16;
#pragma unroll
  for (int r = 0; r < 16; ++r) {
    int gn = nb + r;
    aggs[r][j] = (gn < N) ? agg[(size_t)gn * L + j] : 0.f;
  }
  __syncthreads();
  float ar[16], az[16], an[16];
  const float br = b_ih[j], bz = b_ih[L + j], bn = b_ih[2 * L + j];
#pragma unroll
  for (int n = 0; n < 16; ++n) { ar[n] = br; az[n] = bz; an[n] = bn; }
  const float* wr = w_ih + (size_t)j * L;
  const float* wz = w_ih + (size_t)(L + j) * L;
  const float* wn = w_ih + (size_t)(2 * L + j) * L;
  for (int k = 0; k < L; k += 4) {
    float4 vr = *(const float4*)(wr + k);
    float4 vz = *(const float4*)(wz + k);
    float4 vn = *(const float4*)(wn + k);
#pragma unroll
    for (int n = 0; n < 16; ++n) {
      float4 a = *(const float4*)(&aggs[n][k]);
      ar[n] += vr.x * a.x + vr.y * a.y + vr.z * a.z + vr.w * a.w;
      az[n] += vz.x * a.x + vz.y * a.y + vz.z * a.z + vz.w * a.w;
      an[n] += vn.x * a.x + vn.y * a.y + vn.z * a.z + vn.w * a.w;
    }
  }
#pragma unroll
  for (int n = 0; n < 16; ++n) {
    int gn = nb + n;
    if (gn >= N) continue;
    float ghr = gh[(size_t)gn * 384 + j];
    float ghz = gh[(size_t)gn * 384 + L + j];
    float ghn = gh[(size_t)gn * 384 + 2 * L + j];
    float r = 1.f / (1.f + __expf(-(ar[n] + ghr)));
    float z = 1.f / (1.f + __expf(-(az[n] + ghz)));
    float t = tanhf(an[n] + r * ghn);
    float h = (1.f - z) * t + z * x0[(size_t)gn * L + j];
    m[(size_t)gn * L + j] = fmaxf(h, 0.f);
  }
}

extern "C" void kernel_launch(void* const* d_in, const int* in_sizes, int n_in,
                              void* d_out, int out_size, void* d_ws, size_t ws_size,
                              hipStream_t stream) {
  const float* x     = (const float*)d_in[0];
  const int*   ei    = (const int*)d_in[1];   // [2,E]: first E src, next E dst
  const float* eattr = (const float*)d_in[2];
  const float* lin_w = (const float*)d_in[3];
  const float* lin_b = (const float*)d_in[4];
  const float* gnn_w = (const float*)d_in[5];
  const float* w_ih  = (const float*)d_in[6];
  const float* w_hh  = (const float*)d_in[7];
  const float* b_ih  = (const float*)d_in[8];
  const float* b_hh  = (const float*)d_in[9];
  const float* mu_w  = (const float*)d_in[10];
  const float* mu_b  = (const float*)d_in[11];
  const float* lv_w  = (const float*)d_in[12];
  const float* lv_b  = (const float*)d_in[13];

  char* ws = (char*)d_ws;
  const size_t szNL = (size_t)N_NODES * L * sizeof(float);       // 25.6 MB
  const size_t szGH = (size_t)N_NODES * 3 * L * sizeof(float);   // 76.8 MB
  const size_t szH  = (size_t)T_TYPES * N_NODES * L * sizeof(float); // 102.4 MB
  size_t off = 0;
  float* x0  = (float*)(ws + off); off += szNL;
  float* m   = (float*)(ws + off); off += szNL;
  float* agg = (float*)(ws + off); off += szNL;
  float* gh  = (float*)(ws + off); off += szGH;
  float* H   = (float*)(ws + off); off += szH;
  int* counts  = (int*)(ws + off); off += 50048 * sizeof(int);
  int* offsets = (int*)(ws + off); off += 50048 * sizeof(int);
  int* cursor  = (int*)(ws + off); off += 50048 * sizeof(int);
  int* epacked = (int*)(ws + off); off += (size_t)E_EDGES * sizeof(int);

  dim3 blk(256);

  // ---- CSR build (dst segments constant across steps) ----
  hipMemsetAsync(counts, 0, N_NODES * sizeof(int), stream);
  hist_dst<<<(E_EDGES + 255) / 256, blk, 0, stream>>>(ei, counts);
  scan_counts<<<1, 1024, 0, stream>>>(counts, offsets, N_NODES);
  hipMemcpyAsync(cursor, offsets, N_NODES * sizeof(int),
                 hipMemcpyDeviceToDevice, stream);
  fill_csr<<<(E_EDGES + 255) / 256, blk, 0, stream>>>(ei, eattr, cursor, epacked);

  // ---- encoder ----
  dim3 g_x0((N_NODES + BN - 1) / BN, L / BO);
  matmul_nt<<<g_x0, blk, 0, stream>>>(x, lin_w, lin_b, x0, N_NODES, IN_F, L, 1, 0, 0);

  dim3 g_gh((N_NODES + BN - 1) / BN, (3 * L) / BO);
  matmul_nt<<<g_gh, blk, 0, stream>>>(x0, w_hh, b_hh, gh, N_NODES, L, 3 * L, 0, 0, 0);

  const float* mcur = x0;
  dim3 g_h((N_NODES + BN - 1) / BN, L / BO, 1);
  dim3 g_hz((N_NODES + BN - 1) / BN, L / BO, T_TYPES);
  for (int s = 0; s < STEPS; ++s) {
    const float* Ws = gnn_w + (size_t)s * T_TYPES * L * L;
    matmul_nt<<<g_hz, blk, 0, stream>>>(mcur, Ws, nullptr, H, N_NODES, L, L, 0,
                                        (size_t)L * L, (size_t)N_NODES * L);
    gather_agg<<<(N_NODES + 3) / 4, blk, 0, stream>>>(H, offsets, epacked, agg, N_NODES);
    gru_relu<<<N_NODES / 16, dim3(128), 0, stream>>>(agg, gh, x0, w_ih, b_ih, m, N_NODES);
    mcur = m;
  }

  float* mu = (float*)d_out;
  float* lv = (float*)d_out + (size_t)N_NODES * L;
  matmul_nt<<<g_h, blk, 0, stream>>>(mcur, mu_w, mu_b, mu, N_NODES, L, L, 0, 0, 0);
  matmul_nt<<<g_h, blk, 0, stream>>>(mcur, lv_w, lv_b, lv, N_NODES, L, L, 0, 0, 0);
}

// Round 3
// 1032.188 us; speedup vs baseline: 5.2024x; 1.4798x over previous
//
#include <hip/hip_runtime.h>
#include <hip/hip_bf16.h>
#include <cmath>

#define N_NODES 50000
#define IN_F 64
#define L 128
#define STEPS 3
#define T_TYPES 4
#define E_EDGES 800000

typedef __attribute__((ext_vector_type(8))) __bf16 bf16x8_t;
typedef __attribute__((ext_vector_type(4))) float f32x4;

__device__ inline float bf2f(ushort u) {
  union { uint i; float f; } v; v.i = ((uint)u) << 16; return v.f;
}
__device__ inline ushort f2bf(float f) {
  union { float f; uint u; } v; v.f = f;
  uint u = v.u;
  u += 0x7fffu + ((u >> 16) & 1u);  // RNE
  return (ushort)(u >> 16);
}

// ---------------- fp32 tiled matmul (only for x0: K=64) ----------------
#define BN 64
#define BO 64
#define BK 16
__global__ __launch_bounds__(256) void matmul_nt(
    const float* __restrict__ A, const float* __restrict__ W,
    const float* __restrict__ bias, float* __restrict__ C,
    int N, int K, int OUT, int relu_flag)
{
  __shared__ float As[BN][BK + 1];
  __shared__ float Ws[BO][BK + 1];
  const int tid = threadIdx.x;
  const int n_base = blockIdx.x * BN;
  const int o_base = blockIdx.y * BO;
  const int tx = tid & 15, ty = tid >> 4;
  const int n0 = ty * 4, o0 = tx * 4;
  const int lr = tid >> 2, lc = (tid & 3) * 4;
  float acc[4][4] = {{0.f, 0.f, 0.f, 0.f}};
  for (int kc = 0; kc < K; kc += BK) {
    int gn = n_base + lr;
    float4 av = make_float4(0.f, 0.f, 0.f, 0.f);
    if (gn < N) av = *(const float4*)(A + (size_t)gn * K + kc + lc);
    As[lr][lc + 0] = av.x; As[lr][lc + 1] = av.y;
    As[lr][lc + 2] = av.z; As[lr][lc + 3] = av.w;
    float4 wv = *(const float4*)(W + (size_t)(o_base + lr) * K + kc + lc);
    Ws[lr][lc + 0] = wv.x; Ws[lr][lc + 1] = wv.y;
    Ws[lr][lc + 2] = wv.z; Ws[lr][lc + 3] = wv.w;
    __syncthreads();
#pragma unroll
    for (int kk = 0; kk < BK; ++kk) {
      float a[4], w[4];
#pragma unroll
      for (int i = 0; i < 4; ++i) a[i] = As[n0 + i][kk];
#pragma unroll
      for (int j = 0; j < 4; ++j) w[j] = Ws[o0 + j][kk];
#pragma unroll
      for (int i = 0; i < 4; ++i)
#pragma unroll
        for (int j = 0; j < 4; ++j) acc[i][j] += a[i] * w[j];
    }
    __syncthreads();
  }
#pragma unroll
  for (int i = 0; i < 4; ++i) {
    int gn = n_base + n0 + i;
    if (gn >= N) continue;
    int o = o_base + o0;
    float4 v;
    v.x = acc[i][0] + bias[o + 0]; v.y = acc[i][1] + bias[o + 1];
    v.z = acc[i][2] + bias[o + 2]; v.w = acc[i][3] + bias[o + 3];
    if (relu_flag) {
      v.x = fmaxf(v.x, 0.f); v.y = fmaxf(v.y, 0.f);
      v.z = fmaxf(v.z, 0.f); v.w = fmaxf(v.w, 0.f);
    }
    *(float4*)(C + (size_t)gn * OUT + o) = v;
  }
}

// ---------------- MFMA GEMM: C = A[N,128] @ W[OUT,128]^T ----------------
// KIND 0: f32 out + bias (gh). KIND 2: bf16 out, no bias (H).
// KIND 3: GRU epilogue -> m_bf16. KIND 4: heads split mu/lv.
template<int OUT, int KIND>
__global__ __launch_bounds__(256) void gemm_mfma(
    const ushort* __restrict__ A, const ushort* __restrict__ W,
    const float* __restrict__ bias, float* __restrict__ Cf,
    ushort* __restrict__ Cb, const float* __restrict__ gh,
    const float* __restrict__ x0f, const float* __restrict__ bias2,
    float* __restrict__ Cf2, int N)
{
  constexpr int K = 128;
  constexpr int NOT = OUT / 16;
  const int lane = threadIdx.x & 63;
  const int wave = threadIdx.x >> 6;
  const int r = lane & 15;
  const int kg = lane >> 4;
  const int row0 = (blockIdx.x * 4 + wave) * 16;
  if (row0 >= N) return;

  // A fragments: 16 rows x K=128, register resident
  bf16x8_t af[4];
  {
    int arow = row0 + r;
    if (arow >= N) arow = N - 1;
    const ushort* ap = A + (size_t)arow * K + kg * 8;
#pragma unroll
    for (int kt = 0; kt < 4; ++kt) af[kt] = *(const bf16x8_t*)(ap + kt * 32);
  }

  f32x4 garr[(KIND == 3) ? NOT : 1];
  const ushort* wp = W + (size_t)r * K + kg * 8;

  auto store_tile = [&](const f32x4& acc, int ot) {
#pragma unroll
    for (int reg = 0; reg < 4; ++reg) {
      int n = row0 + kg * 4 + reg;
      if (n >= N) continue;
      int o = ot * 16 + r;
      float v = acc[reg];
      if constexpr (KIND == 0) {
        Cf[(size_t)n * OUT + o] = v + bias[o];
      } else if constexpr (KIND == 2) {
        Cb[(size_t)n * OUT + o] = f2bf(v);
      } else if constexpr (KIND == 4) {
        if (o < 128) Cf[(size_t)n * 128 + o] = v + bias[o];
        else Cf2[(size_t)n * 128 + (o - 128)] = v + bias2[o - 128];
      }
    }
  };

#pragma unroll
  for (int otp = 0; otp < NOT / 2; ++otp) {
    bf16x8_t w0[4], w1[4];
#pragma unroll
    for (int kt = 0; kt < 4; ++kt) {
      w0[kt] = *(const bf16x8_t*)(wp + (size_t)(2 * otp) * 16 * K + kt * 32);
      w1[kt] = *(const bf16x8_t*)(wp + (size_t)(2 * otp + 1) * 16 * K + kt * 32);
    }
    f32x4 a0 = {0.f, 0.f, 0.f, 0.f}, a1 = {0.f, 0.f, 0.f, 0.f};
#pragma unroll
    for (int kt = 0; kt < 4; ++kt) {
      a0 = __builtin_amdgcn_mfma_f32_16x16x32_bf16(af[kt], w0[kt], a0, 0, 0, 0);
      a1 = __builtin_amdgcn_mfma_f32_16x16x32_bf16(af[kt], w1[kt], a1, 0, 0, 0);
    }
    if constexpr (KIND == 3) {
      garr[2 * otp] = a0;
      garr[2 * otp + 1] = a1;
    } else {
      store_tile(a0, 2 * otp);
      store_tile(a1, 2 * otp + 1);
    }
  }

  if constexpr (KIND == 3) {
    // lane holds gi triples: gate j at (ot = j/16 + gate*8), col r = j%16
#pragma unroll
    for (int jg = 0; jg < 8; ++jg) {
      int j = jg * 16 + r;
      float br = bias[j], bz = bias[128 + j], bn = bias[256 + j];
#pragma unroll
      for (int reg = 0; reg < 4; ++reg) {
        int n = row0 + kg * 4 + reg;
        if (n >= N) continue;
        float gir = garr[jg][reg] + br;
        float giz = garr[8 + jg][reg] + bz;
        float gin = garr[16 + jg][reg] + bn;
        const float* ghp = gh + (size_t)n * 384;
        float rr = 1.f / (1.f + expf(-(gir + ghp[j])));
        float zz = 1.f / (1.f + expf(-(giz + ghp[128 + j])));
        float nn = tanhf(gin + rr * ghp[256 + j]);
        float h = (1.f - zz) * nn + zz * x0f[(size_t)n * 128 + j];
        Cb[(size_t)n * 128 + j] = f2bf(fmaxf(h, 0.f));
      }
    }
  }
}

// ---------------- weight conversion f32 -> bf16 (packed segments) ----------------
#define WOFF_LIN 0
#define WOFF_WHH 8192
#define WOFF_WIH 57344
#define WOFF_GNN 106496
#define WOFF_HEADS 303104
#define WTOT 335872

__global__ __launch_bounds__(256) void convert_weights(
    const float* __restrict__ lin_w, const float* __restrict__ w_hh,
    const float* __restrict__ w_ih, const float* __restrict__ gnn_w,
    const float* __restrict__ mu_w, const float* __restrict__ lv_w,
    ushort* __restrict__ wsb)
{
  int i = blockIdx.x * 256 + threadIdx.x;
  if (i >= WTOT) return;
  float v;
  if (i < WOFF_WHH) v = lin_w[i];
  else if (i < WOFF_WIH) v = w_hh[i - WOFF_WHH];
  else if (i < WOFF_GNN) v = w_ih[i - WOFF_WIH];
  else if (i < WOFF_HEADS) v = gnn_w[i - WOFF_GNN];
  else {
    int k = i - WOFF_HEADS;
    v = (k < 16384) ? mu_w[k] : lv_w[k - 16384];
  }
  wsb[i] = f2bf(v);
}

__global__ __launch_bounds__(256) void cvt_f32_bf16(
    const float* __restrict__ in, ushort* __restrict__ out, int n)
{
  int i = blockIdx.x * 256 + threadIdx.x;
  if (i < n) out[i] = f2bf(in[i]);
}

// ---------------- CSR build ----------------
__global__ __launch_bounds__(256) void hist_dst(
    const int* __restrict__ ei, int* __restrict__ counts)
{
  int e = blockIdx.x * 256 + threadIdx.x;
  if (e >= E_EDGES) return;
  atomicAdd(&counts[ei[E_EDGES + e]], 1);
}

__global__ __launch_bounds__(1024) void scan_counts(
    const int* __restrict__ counts, int* __restrict__ offsets, int n)
{
  __shared__ int ls[1024];
  __shared__ int carry_s;
  const int tid = threadIdx.x;
  if (tid == 0) carry_s = 0;
  __syncthreads();
  for (int start = 0; start < n; start += 1024) {
    int i = start + tid;
    int v = (i < n) ? counts[i] : 0;
    ls[tid] = v;
    __syncthreads();
    for (int off = 1; off < 1024; off <<= 1) {
      int t = (tid >= off) ? ls[tid - off] : 0;
      __syncthreads();
      ls[tid] += t;
      __syncthreads();
    }
    int c = carry_s;
    if (i < n) offsets[i] = c + ls[tid] - v;  // exclusive
    __syncthreads();
    if (tid == 0) carry_s = c + ls[1023];
    __syncthreads();
  }
}

__global__ __launch_bounds__(256) void fill_csr(
    const int* __restrict__ ei, const float* __restrict__ ea,
    int* __restrict__ cursor, int* __restrict__ epacked)
{
  int e = blockIdx.x * 256 + threadIdx.x;
  if (e >= E_EDGES) return;
  const float* a = ea + (size_t)e * T_TYPES;
  float bv = a[0]; int bi = 0;
#pragma unroll
  for (int t = 1; t < T_TYPES; ++t) {
    float v = a[t];
    if (v > bv) { bv = v; bi = t; }
  }
  int d = ei[E_EDGES + e];
  int pos = atomicAdd(&cursor[d], 1);
  epacked[pos] = (bi << 20) | ei[e];
}

// ---------------- gather: agg_bf16[d] = bf16(2 * sum_e H[src_e, t_e*128..]) ----------------
__global__ __launch_bounds__(256) void gather_agg_b(
    const ushort* __restrict__ H, const int* __restrict__ offsets,
    const int* __restrict__ epacked, ushort* __restrict__ aggb, int nNodes)
{
  const int wave = threadIdx.x >> 6, lane = threadIdx.x & 63;
  const int node = blockIdx.x * 4 + wave;
  if (node >= nNodes) return;
  const int beg = offsets[node];
  const int end = (node + 1 < nNodes) ? offsets[node + 1] : E_EDGES;
  float a0 = 0.f, a1 = 0.f;
  for (int j = beg; j < end; ++j) {
    int p = epacked[j];
    int src = p & 0xFFFFF;
    int t = p >> 20;
    uint h = *(const uint*)(H + (size_t)src * 512 + t * 128 + lane * 2);
    a0 += bf2f((ushort)(h & 0xffff));
    a1 += bf2f((ushort)(h >> 16));
  }
  uint out = (uint)f2bf(2.f * a0) | ((uint)f2bf(2.f * a1) << 16);
  *(uint*)(aggb + (size_t)node * 128 + lane * 2) = out;
}

extern "C" void kernel_launch(void* const* d_in, const int* in_sizes, int n_in,
                              void* d_out, int out_size, void* d_ws, size_t ws_size,
                              hipStream_t stream) {
  const float* x     = (const float*)d_in[0];
  const int*   ei    = (const int*)d_in[1];
  const float* eattr = (const float*)d_in[2];
  const float* lin_w = (const float*)d_in[3];
  const float* lin_b = (const float*)d_in[4];
  const float* gnn_w = (const float*)d_in[5];
  const float* w_ih  = (const float*)d_in[6];
  const float* w_hh  = (const float*)d_in[7];
  const float* b_ih  = (const float*)d_in[8];
  const float* b_hh  = (const float*)d_in[9];
  const float* mu_w  = (const float*)d_in[10];
  const float* mu_b  = (const float*)d_in[11];
  const float* lv_w  = (const float*)d_in[12];
  const float* lv_b  = (const float*)d_in[13];

  char* ws = (char*)d_ws;
  size_t off = 0;
  float*  x0f = (float*)(ws + off);  off += (size_t)N_NODES * L * 4;        // 25.6MB
  float*  gh  = (float*)(ws + off);  off += (size_t)N_NODES * 3 * L * 4;    // 76.8MB
  ushort* x0b = (ushort*)(ws + off); off += (size_t)N_NODES * L * 2;        // 12.8MB
  ushort* m_b = (ushort*)(ws + off); off += (size_t)N_NODES * L * 2;        // 12.8MB
  ushort* aggb= (ushort*)(ws + off); off += (size_t)N_NODES * L * 2;        // 12.8MB
  ushort* H   = (ushort*)(ws + off); off += (size_t)N_NODES * 4 * L * 2;    // 51.2MB
  ushort* wsb = (ushort*)(ws + off); off += (size_t)WTOT * 2;               // 0.67MB
  int* counts  = (int*)(ws + off); off += 50048 * 4;
  int* offsets = (int*)(ws + off); off += 50048 * 4;
  int* cursor  = (int*)(ws + off); off += 50048 * 4;
  int* epacked = (int*)(ws + off); off += (size_t)E_EDGES * 4;

  dim3 blk(256);
  const int GEMM_GRID = (N_NODES + 63) / 64;  // 782

  convert_weights<<<(WTOT + 255) / 256, blk, 0, stream>>>(
      lin_w, w_hh, w_ih, gnn_w, mu_w, lv_w, wsb);

  // CSR (constant across steps)
  hipMemsetAsync(counts, 0, N_NODES * sizeof(int), stream);
  hist_dst<<<(E_EDGES + 255) / 256, blk, 0, stream>>>(ei, counts);
  scan_counts<<<1, 1024, 0, stream>>>(counts, offsets, N_NODES);
  hipMemcpyAsync(cursor, offsets, N_NODES * sizeof(int),
                 hipMemcpyDeviceToDevice, stream);
  fill_csr<<<(E_EDGES + 255) / 256, blk, 0, stream>>>(ei, eattr, cursor, epacked);

  // x0 = relu(x @ lin_w^T + lin_b)  (fp32, K=64)
  dim3 g_x0((N_NODES + BN - 1) / BN, L / BO);
  matmul_nt<<<g_x0, blk, 0, stream>>>(x, lin_w, lin_b, x0f, N_NODES, IN_F, L, 1);
  cvt_f32_bf16<<<((N_NODES * L) + 255) / 256, blk, 0, stream>>>(x0f, x0b, N_NODES * L);

  // gh = x0 @ w_hh^T + b_hh (f32 out)
  gemm_mfma<384, 0><<<GEMM_GRID, blk, 0, stream>>>(
      x0b, wsb + WOFF_WHH, b_hh, gh, nullptr, nullptr, nullptr, nullptr, nullptr, N_NODES);

  const ushort* mcur = x0b;
  for (int s = 0; s < STEPS; ++s) {
    // H[n, t*128+c] = m @ gnn_w[s]^T  (bf16 out)
    gemm_mfma<512, 2><<<GEMM_GRID, blk, 0, stream>>>(
        mcur, wsb + WOFF_GNN + (size_t)s * 4 * L * L, nullptr, nullptr, H,
        nullptr, nullptr, nullptr, nullptr, N_NODES);
    gather_agg_b<<<(N_NODES + 3) / 4, blk, 0, stream>>>(H, offsets, epacked, aggb, N_NODES);
    // m = relu(GRU(agg, x0))  fused epilogue, bf16 out
    gemm_mfma<384, 3><<<GEMM_GRID, blk, 0, stream>>>(
        aggb, wsb + WOFF_WIH, b_ih, nullptr, m_b, gh, x0f, nullptr, nullptr, N_NODES);
    mcur = m_b;
  }

  // heads: [mu; lv] = m @ [mu_w; lv_w]^T + bias, split write to d_out
  float* mu = (float*)d_out;
  float* lv = (float*)d_out + (size_t)N_NODES * L;
  gemm_mfma<256, 4><<<GEMM_GRID, blk, 0, stream>>>(
      m_b, wsb + WOFF_HEADS, mu_b, mu, nullptr, nullptr, nullptr, lv_b, lv, N_NODES);
}

// Round 4
// 775.114 us; speedup vs baseline: 6.9279x; 1.3317x over previous
//
#include <hip/hip_runtime.h>
#include <hip/hip_bf16.h>
#include <cmath>

#define N_NODES 50000
#define IN_F 64
#define L 128
#define STEPS 3
#define T_TYPES 4
#define E_EDGES 800000

typedef __attribute__((ext_vector_type(8))) __bf16 bf16x8_t;
typedef __attribute__((ext_vector_type(4))) float f32x4;

__device__ inline float bf2f(ushort u) {
  union { uint i; float f; } v; v.i = ((uint)u) << 16; return v.f;
}
__device__ inline ushort f2bf(float f) {
  union { float f; uint u; } v; v.f = f;
  uint u = v.u;
  u += 0x7fffu + ((u >> 16) & 1u);  // RNE
  return (ushort)(u >> 16);
}

// ---------------- fp32 tiled matmul for x0 (K=64), writes bf16 ----------------
#define BN 64
#define BO 64
#define BK 16
__global__ __launch_bounds__(256) void matmul_x0(
    const float* __restrict__ A, const float* __restrict__ W,
    const float* __restrict__ bias, ushort* __restrict__ Cb,
    int N, int K, int OUT)
{
  __shared__ float As[BN][BK + 1];
  __shared__ float Ws[BO][BK + 1];
  const int tid = threadIdx.x;
  const int n_base = blockIdx.x * BN;
  const int o_base = blockIdx.y * BO;
  const int tx = tid & 15, ty = tid >> 4;
  const int n0 = ty * 4, o0 = tx * 4;
  const int lr = tid >> 2, lc = (tid & 3) * 4;
  float acc[4][4] = {{0.f, 0.f, 0.f, 0.f}};
  for (int kc = 0; kc < K; kc += BK) {
    int gn = n_base + lr;
    float4 av = make_float4(0.f, 0.f, 0.f, 0.f);
    if (gn < N) av = *(const float4*)(A + (size_t)gn * K + kc + lc);
    As[lr][lc + 0] = av.x; As[lr][lc + 1] = av.y;
    As[lr][lc + 2] = av.z; As[lr][lc + 3] = av.w;
    float4 wv = *(const float4*)(W + (size_t)(o_base + lr) * K + kc + lc);
    Ws[lr][lc + 0] = wv.x; Ws[lr][lc + 1] = wv.y;
    Ws[lr][lc + 2] = wv.z; Ws[lr][lc + 3] = wv.w;
    __syncthreads();
#pragma unroll
    for (int kk = 0; kk < BK; ++kk) {
      float a[4], w[4];
#pragma unroll
      for (int i = 0; i < 4; ++i) a[i] = As[n0 + i][kk];
#pragma unroll
      for (int j = 0; j < 4; ++j) w[j] = Ws[o0 + j][kk];
#pragma unroll
      for (int i = 0; i < 4; ++i)
#pragma unroll
        for (int j = 0; j < 4; ++j) acc[i][j] += a[i] * w[j];
    }
    __syncthreads();
  }
#pragma unroll
  for (int i = 0; i < 4; ++i) {
    int gn = n_base + n0 + i;
    if (gn >= N) continue;
    int o = o_base + o0;
    float v0 = fmaxf(acc[i][0] + bias[o + 0], 0.f);
    float v1 = fmaxf(acc[i][1] + bias[o + 1], 0.f);
    float v2 = fmaxf(acc[i][2] + bias[o + 2], 0.f);
    float v3 = fmaxf(acc[i][3] + bias[o + 3], 0.f);
    uint2 pk;
    pk.x = (uint)f2bf(v0) | ((uint)f2bf(v1) << 16);
    pk.y = (uint)f2bf(v2) | ((uint)f2bf(v3) << 16);
    *(uint2*)(Cb + (size_t)gn * OUT + o) = pk;
  }
}

// ---------------- MFMA GEMM: A[N,128] @ W[OUT,128]^T, 32 rows/wave ----------------
// KIND 0: bf16 out + bias (gh). KIND 2: bf16 out, no bias (H).
// KIND 3: GRU gate-triple epilogue -> m bf16. KIND 4: heads split mu/lv (f32).
template<int OUT, int KIND>
__global__ __launch_bounds__(256) void gemm_mfma(
    const ushort* __restrict__ A, const ushort* __restrict__ W,
    const float* __restrict__ bias, float* __restrict__ Cf,
    ushort* __restrict__ Cb, const ushort* __restrict__ ghb,
    const ushort* __restrict__ x0b, const float* __restrict__ bias2,
    float* __restrict__ Cf2, int N)
{
  constexpr int K = 128;
  constexpr int NOT = OUT / 16;
  const int lane = threadIdx.x & 63;
  const int wave = threadIdx.x >> 6;
  const int r = lane & 15;
  const int kg = lane >> 4;
  const int row0 = (blockIdx.x * 8 + wave * 2) * 16;  // 2 row-tiles per wave
  if (row0 >= N) return;

  bf16x8_t af[2][4];
#pragma unroll
  for (int rt = 0; rt < 2; ++rt) {
    int arow = row0 + rt * 16 + r;
    if (arow >= N) arow = N - 1;
    const ushort* ap = A + (size_t)arow * K + kg * 8;
#pragma unroll
    for (int kt = 0; kt < 4; ++kt) af[rt][kt] = *(const bf16x8_t*)(ap + kt * 32);
  }
  const ushort* wp = W + (size_t)r * K + kg * 8;

  if constexpr (KIND != 3) {
#pragma unroll
    for (int otp = 0; otp < NOT / 2; ++otp) {
      bf16x8_t w0[4], w1[4];
#pragma unroll
      for (int kt = 0; kt < 4; ++kt) {
        w0[kt] = *(const bf16x8_t*)(wp + (size_t)(2 * otp) * 16 * K + kt * 32);
        w1[kt] = *(const bf16x8_t*)(wp + (size_t)(2 * otp + 1) * 16 * K + kt * 32);
      }
      f32x4 acc[2][2] = {{{0.f,0.f,0.f,0.f},{0.f,0.f,0.f,0.f}},
                         {{0.f,0.f,0.f,0.f},{0.f,0.f,0.f,0.f}}};
#pragma unroll
      for (int kt = 0; kt < 4; ++kt) {
#pragma unroll
        for (int rt = 0; rt < 2; ++rt) {
          acc[rt][0] = __builtin_amdgcn_mfma_f32_16x16x32_bf16(af[rt][kt], w0[kt], acc[rt][0], 0, 0, 0);
          acc[rt][1] = __builtin_amdgcn_mfma_f32_16x16x32_bf16(af[rt][kt], w1[kt], acc[rt][1], 0, 0, 0);
        }
      }
#pragma unroll
      for (int rt = 0; rt < 2; ++rt) {
#pragma unroll
        for (int oi = 0; oi < 2; ++oi) {
          int ot = 2 * otp + oi;
          int o = ot * 16 + r;
#pragma unroll
          for (int reg = 0; reg < 4; ++reg) {
            int n = row0 + rt * 16 + kg * 4 + reg;
            if (n >= N) continue;
            float v = acc[rt][oi][reg];
            if constexpr (KIND == 0) {
              Cb[(size_t)n * OUT + o] = f2bf(v + bias[o]);
            } else if constexpr (KIND == 2) {
              Cb[(size_t)n * OUT + o] = f2bf(v);
            } else if constexpr (KIND == 4) {
              if (o < 128) Cf[(size_t)n * 128 + o] = v + bias[o];
              else Cf2[(size_t)n * 128 + (o - 128)] = v + bias2[o - 128];
            }
          }
        }
      }
    }
  } else {
    // GRU: gate j cols live at out-tiles {jg, 8+jg, 16+jg}
#pragma unroll
    for (int jg = 0; jg < 8; ++jg) {
      bf16x8_t wr_[4], wz_[4], wn_[4];
#pragma unroll
      for (int kt = 0; kt < 4; ++kt) {
        wr_[kt] = *(const bf16x8_t*)(wp + (size_t)(jg) * 16 * K + kt * 32);
        wz_[kt] = *(const bf16x8_t*)(wp + (size_t)(8 + jg) * 16 * K + kt * 32);
        wn_[kt] = *(const bf16x8_t*)(wp + (size_t)(16 + jg) * 16 * K + kt * 32);
      }
      f32x4 ar[2] = {{0.f,0.f,0.f,0.f},{0.f,0.f,0.f,0.f}};
      f32x4 az[2] = {{0.f,0.f,0.f,0.f},{0.f,0.f,0.f,0.f}};
      f32x4 an[2] = {{0.f,0.f,0.f,0.f},{0.f,0.f,0.f,0.f}};
#pragma unroll
      for (int kt = 0; kt < 4; ++kt) {
#pragma unroll
        for (int rt = 0; rt < 2; ++rt) {
          ar[rt] = __builtin_amdgcn_mfma_f32_16x16x32_bf16(af[rt][kt], wr_[kt], ar[rt], 0, 0, 0);
          az[rt] = __builtin_amdgcn_mfma_f32_16x16x32_bf16(af[rt][kt], wz_[kt], az[rt], 0, 0, 0);
          an[rt] = __builtin_amdgcn_mfma_f32_16x16x32_bf16(af[rt][kt], wn_[kt], an[rt], 0, 0, 0);
        }
      }
      int j = jg * 16 + r;
      float br = bias[j], bz = bias[128 + j], bn = bias[256 + j];
#pragma unroll
      for (int rt = 0; rt < 2; ++rt) {
#pragma unroll
        for (int reg = 0; reg < 4; ++reg) {
          int n = row0 + rt * 16 + kg * 4 + reg;
          if (n >= N) continue;
          const ushort* ghp = ghb + (size_t)n * 384;
          float gir = ar[rt][reg] + br + bf2f(ghp[j]);
          float giz = az[rt][reg] + bz + bf2f(ghp[128 + j]);
          float ghn = bf2f(ghp[256 + j]);
          float rr = 1.f / (1.f + expf(-gir));
          float zz = 1.f / (1.f + expf(-giz));
          float nn = tanhf(an[rt][reg] + bn + rr * ghn);
          float x0v = bf2f(x0b[(size_t)n * 128 + j]);
          float h = (1.f - zz) * nn + zz * x0v;
          Cb[(size_t)n * 128 + j] = f2bf(fmaxf(h, 0.f));
        }
      }
    }
  }
}

// ---------------- weight conversion f32 -> bf16 (packed segments) ----------------
#define WOFF_WHH 0
#define WOFF_WIH 49152
#define WOFF_GNN 98304
#define WOFF_HEADS 294912
#define WTOT 327680

__global__ __launch_bounds__(256) void convert_weights(
    const float* __restrict__ w_hh, const float* __restrict__ w_ih,
    const float* __restrict__ gnn_w, const float* __restrict__ mu_w,
    const float* __restrict__ lv_w, ushort* __restrict__ wsb)
{
  int i = blockIdx.x * 256 + threadIdx.x;
  if (i >= WTOT) return;
  float v;
  if (i < WOFF_WIH) v = w_hh[i - WOFF_WHH];
  else if (i < WOFF_GNN) v = w_ih[i - WOFF_WIH];
  else if (i < WOFF_HEADS) v = gnn_w[i - WOFF_GNN];
  else {
    int k = i - WOFF_HEADS;
    v = (k < 16384) ? mu_w[k] : lv_w[k - 16384];
  }
  wsb[i] = f2bf(v);
}

// ---------------- CSR build ----------------
__global__ __launch_bounds__(256) void hist_dst(
    const int* __restrict__ ei, int* __restrict__ counts)
{
  int e = blockIdx.x * 256 + threadIdx.x;
  if (e >= E_EDGES) return;
  atomicAdd(&counts[ei[E_EDGES + e]], 1);
}

__global__ __launch_bounds__(1024) void scan_counts(
    const int* __restrict__ counts, int* __restrict__ offsets, int n)
{
  __shared__ int ls[1024];
  __shared__ int carry_s;
  const int tid = threadIdx.x;
  if (tid == 0) carry_s = 0;
  __syncthreads();
  for (int start = 0; start < n; start += 1024) {
    int i = start + tid;
    int v = (i < n) ? counts[i] : 0;
    ls[tid] = v;
    __syncthreads();
    for (int off = 1; off < 1024; off <<= 1) {
      int t = (tid >= off) ? ls[tid - off] : 0;
      __syncthreads();
      ls[tid] += t;
      __syncthreads();
    }
    int c = carry_s;
    if (i < n) offsets[i] = c + ls[tid] - v;  // exclusive
    __syncthreads();
    if (tid == 0) carry_s = c + ls[1023];
    __syncthreads();
  }
}

__global__ __launch_bounds__(256) void fill_csr(
    const int* __restrict__ ei, const float* __restrict__ ea,
    int* __restrict__ cursor, int* __restrict__ epacked)
{
  int e = blockIdx.x * 256 + threadIdx.x;
  if (e >= E_EDGES) return;
  const float* a = ea + (size_t)e * T_TYPES;
  float bv = a[0]; int bi = 0;
#pragma unroll
  for (int t = 1; t < T_TYPES; ++t) {
    float v = a[t];
    if (v > bv) { bv = v; bi = t; }
  }
  int d = ei[E_EDGES + e];
  int pos = atomicAdd(&cursor[d], 1);
  epacked[pos] = (bi << 20) | ei[e];
}

// ---------------- gather: agg_bf16[d] = bf16(2 * sum_e H[src_e, t_e*128..]) ----------------
__global__ __launch_bounds__(256) void gather_agg_b(
    const ushort* __restrict__ H, const int* __restrict__ offsets,
    const int* __restrict__ epacked, ushort* __restrict__ aggb, int nNodes)
{
  const int wave = threadIdx.x >> 6, lane = threadIdx.x & 63;
  const int node = blockIdx.x * 4 + wave;
  if (node >= nNodes) return;
  const int beg = offsets[node];
  const int end = (node + 1 < nNodes) ? offsets[node + 1] : E_EDGES;
  float a0 = 0.f, a1 = 0.f;
  int j = beg;
  for (; j + 1 < end; j += 2) {
    int p0 = epacked[j], p1 = epacked[j + 1];
    uint h0 = *(const uint*)(H + (size_t)(p0 & 0xFFFFF) * 512 + (p0 >> 20) * 128 + lane * 2);
    uint h1 = *(const uint*)(H + (size_t)(p1 & 0xFFFFF) * 512 + (p1 >> 20) * 128 + lane * 2);
    a0 += bf2f((ushort)(h0 & 0xffff)) + bf2f((ushort)(h1 & 0xffff));
    a1 += bf2f((ushort)(h0 >> 16)) + bf2f((ushort)(h1 >> 16));
  }
  if (j < end) {
    int p0 = epacked[j];
    uint h0 = *(const uint*)(H + (size_t)(p0 & 0xFFFFF) * 512 + (p0 >> 20) * 128 + lane * 2);
    a0 += bf2f((ushort)(h0 & 0xffff));
    a1 += bf2f((ushort)(h0 >> 16));
  }
  uint out = (uint)f2bf(2.f * a0) | ((uint)f2bf(2.f * a1) << 16);
  *(uint*)(aggb + (size_t)node * 128 + lane * 2) = out;
}

extern "C" void kernel_launch(void* const* d_in, const int* in_sizes, int n_in,
                              void* d_out, int out_size, void* d_ws, size_t ws_size,
                              hipStream_t stream) {
  const float* x     = (const float*)d_in[0];
  const int*   ei    = (const int*)d_in[1];
  const float* eattr = (const float*)d_in[2];
  const float* lin_w = (const float*)d_in[3];
  const float* lin_b = (const float*)d_in[4];
  const float* gnn_w = (const float*)d_in[5];
  const float* w_ih  = (const float*)d_in[6];
  const float* w_hh  = (const float*)d_in[7];
  const float* b_ih  = (const float*)d_in[8];
  const float* b_hh  = (const float*)d_in[9];
  const float* mu_w  = (const float*)d_in[10];
  const float* mu_b  = (const float*)d_in[11];
  const float* lv_w  = (const float*)d_in[12];
  const float* lv_b  = (const float*)d_in[13];

  char* ws = (char*)d_ws;
  size_t off = 0;
  ushort* x0b = (ushort*)(ws + off); off += (size_t)N_NODES * L * 2;        // 12.8MB
  ushort* ghb = (ushort*)(ws + off); off += (size_t)N_NODES * 3 * L * 2;    // 38.4MB
  ushort* m_b = (ushort*)(ws + off); off += (size_t)N_NODES * L * 2;        // 12.8MB
  ushort* aggb= (ushort*)(ws + off); off += (size_t)N_NODES * L * 2;        // 12.8MB
  ushort* H   = (ushort*)(ws + off); off += (size_t)N_NODES * 4 * L * 2;    // 51.2MB
  ushort* wsb = (ushort*)(ws + off); off += (size_t)WTOT * 2;               // 0.66MB
  int* counts  = (int*)(ws + off); off += 50048 * 4;
  int* offsets = (int*)(ws + off); off += 50048 * 4;
  int* cursor  = (int*)(ws + off); off += 50048 * 4;
  int* epacked = (int*)(ws + off); off += (size_t)E_EDGES * 4;

  dim3 blk(256);
  const int GEMM_GRID = (N_NODES + 127) / 128;  // 391, 128 rows/block

  convert_weights<<<(WTOT + 255) / 256, blk, 0, stream>>>(
      w_hh, w_ih, gnn_w, mu_w, lv_w, wsb);

  // CSR (constant across steps)
  hipMemsetAsync(counts, 0, N_NODES * sizeof(int), stream);
  hist_dst<<<(E_EDGES + 255) / 256, blk, 0, stream>>>(ei, counts);
  scan_counts<<<1, 1024, 0, stream>>>(counts, offsets, N_NODES);
  hipMemcpyAsync(cursor, offsets, N_NODES * sizeof(int),
                 hipMemcpyDeviceToDevice, stream);
  fill_csr<<<(E_EDGES + 255) / 256, blk, 0, stream>>>(ei, eattr, cursor, epacked);

  // x0 = relu(x @ lin_w^T + lin_b) -> bf16
  dim3 g_x0((N_NODES + BN - 1) / BN, L / BO);
  matmul_x0<<<g_x0, blk, 0, stream>>>(x, lin_w, lin_b, x0b, N_NODES, IN_F, L);

  // gh = x0 @ w_hh^T + b_hh -> bf16
  gemm_mfma<384, 0><<<GEMM_GRID, blk, 0, stream>>>(
      x0b, wsb + WOFF_WHH, b_hh, nullptr, ghb, nullptr, nullptr, nullptr, nullptr, N_NODES);

  const ushort* mcur = x0b;
  for (int s = 0; s < STEPS; ++s) {
    gemm_mfma<512, 2><<<GEMM_GRID, blk, 0, stream>>>(
        mcur, wsb + WOFF_GNN + (size_t)s * 4 * L * L, nullptr, nullptr, H,
        nullptr, nullptr, nullptr, nullptr, N_NODES);
    gather_agg_b<<<(N_NODES + 3) / 4, blk, 0, stream>>>(H, offsets, epacked, aggb, N_NODES);
    gemm_mfma<384, 3><<<GEMM_GRID, blk, 0, stream>>>(
        aggb, wsb + WOFF_WIH, b_ih, nullptr, m_b, ghb, x0b, nullptr, nullptr, N_NODES);
    mcur = m_b;
  }

  float* mu = (float*)d_out;
  float* lv = (float*)d_out + (size_t)N_NODES * L;
  gemm_mfma<256, 4><<<GEMM_GRID, blk, 0, stream>>>(
      m_b, wsb + WOFF_HEADS, mu_b, mu, nullptr, nullptr, nullptr, lv_b, lv, N_NODES);
}